// Round 8
// baseline (416.543 us; speedup 1.0000x reference)
//
#include <hip/hip_runtime.h>
#include <hip/hip_bf16.h>

#define NE 50000
#define NA 800000
#define NC 100000

typedef _Float16 f16;
typedef f16 half8 __attribute__((ext_vector_type(8)));
typedef f16 f16x2 __attribute__((ext_vector_type(2)));
typedef f16 f16x4 __attribute__((ext_vector_type(4)));
typedef float f32x4 __attribute__((ext_vector_type(4)));

// f16-element offsets inside the converted-weight arena
#define OFF_ENC1 0
#define OFF_ENC2 8192
#define OFF_MSGPQ 24576    // 3 layers x 32768 (P block 16384 + Q block 16384)
#define OFF_UPD1 122880    // 3 layers x 32768, fused layout [n][256]
#define OFF_UPD2 221184    // 3 layers x 16384
#define OFF_PREDPQ 270336  // 32768
#define OFF_PREDW2 303104  // 16384
#define TOTAL_WT 319488

#define R_FUSE 49536       // 3*129 groups x 128 threads
#define R_WT 270336
#define R_Z 50000
#define PTOT (R_FUSE + R_WT + R_Z)

struct KP {
    const float* edge_features;
    const int *adj_dst, *adj_src, *cand_i, *cand_j;
    const float *enc_b1, *enc_b2;
    const float *msg_b1, *msg_W2, *msg_b2;
    const float *upd_W1, *upd_b1, *upd_b2;
    const float *pred_b1, *pred_b2, *pred_W3, *pred_b3;
    f16* wt;
    float* fbias;
    f16 *eA, *eB, *P0, *Q0, *P1, *Q1, *mbuf;
    int *segStart, *segEnd;
    float *outP, *outL;
    const float* wsrc[20];
    int wK[20], wOff[20], wStr[20], wCum[21];
};

// ---------------- shared device bodies ----------------

__device__ __forceinline__ void prep_item(const KP& p, int gid) {
    if (gid < R_FUSE) {
        // fused W2U = msg_W2 @ upd_W1[128:256] and fbias; coalesced per 128-group
        int g = gid >> 7, n = gid & 127;
        int l = g / 129, kk = g % 129;
        const float* U1b = p.upd_W1 + (size_t)l * 32768 + 16384;
        if (kk < 128) {
            const float* w2row = p.msg_W2 + (size_t)l * 16384 + (size_t)kk * 128;
            float s = 0.f;
            for (int m = 0; m < 128; ++m) s += w2row[m] * U1b[m * 128 + n];
            p.wt[OFF_UPD1 + l * 32768 + n * 256 + 128 + kk] = (f16)s;
        } else {
            const float* b2 = p.msg_b2 + l * 128;
            float s = p.upd_b1[l * 128 + n];
            for (int m = 0; m < 128; ++m) s += b2[m] * U1b[m * 128 + n];
            p.fbias[l * 128 + n] = s;
        }
    } else if (gid < R_FUSE + R_WT) {
        int e = gid - R_FUSE;
        int j = 0;
#pragma unroll
        for (int i = 1; i < 20; ++i) j += (e >= p.wCum[i]) ? 1 : 0;
        int r = e - p.wCum[j];
        int K = p.wK[j];
        int k = r % K, n = r / K;
        p.wt[p.wOff[j] + n * p.wStr[j] + k] = (f16)p.wsrc[j][(size_t)k * 128 + n];
    } else if (gid < PTOT) {
        int z = gid - (R_FUSE + R_WT);
        p.segStart[z] = 0;
        p.segEnd[z] = 0;
    }
}

__device__ __forceinline__ void degseg_item(const KP& p, int i) {
    int d = p.adj_dst[i];
    if (i == 0 || p.adj_dst[i - 1] != d) p.segStart[d] = i;
    if (i == NA - 1 || p.adj_dst[i + 1] != d) p.segEnd[d] = i + 1;
}

// P/Q are stored CHANNEL-PACKED: layout [8 groups][NE][16 ch] f16.
// Element (row, ch) lives at ((ch>>4)*NE + row)*16 + (ch&15).

// one 64-row tile: GEMM1(K1) -> relu -> GEMM2 -> e' -> fused P/Q GEMM.
// MSG: stage cols 128..255 of A from in1 (precomputed message buffer).
// F32IN: stage A from raw f32 in0f (convert on the fly) instead of f16 in0.
// Weight fragments are explicitly double-buffered (kc+1 prefetch) in GEMM1/2.
template <int K1, bool MSG, bool F32IN>
__device__ __forceinline__ void do_tile(
    char* SMEM, int tile, const f16* __restrict__ in0, const float* __restrict__ in0f,
    const f16* __restrict__ in1,
    const f16* __restrict__ w1t, const int w1s, const float* __restrict__ b1v,
    const f16* __restrict__ w2t, const float* __restrict__ b2v, const bool reluOut,
    f16* __restrict__ oute,
    const f16* __restrict__ wpq, const float* __restrict__ bPp,
    f16* __restrict__ Pout, f16* __restrict__ Qout) {
    constexpr int SA = K1 + 8;   // f16 stride
    constexpr int SH = 136;      // f16 stride for H/E
    constexpr int NKC = K1 / 32;
    f16* Abuf = (f16*)SMEM;
    f16* Hbuf = (f16*)SMEM;                  // aliases Abuf low (dead after GEMM1)
    f16* Ebuf = (f16*)(SMEM + 17408);        // after Hbuf; overlaps dead Abuf top
    const int t = threadIdx.x, lane = t & 63, wave = t >> 6;
    const int quad = lane >> 4, mn = lane & 15, n0 = wave * 32;
    const int rbase = tile << 6;

    // ---- stage A-tile left half (or all of it for K1==64) from in0/in0f
    if constexpr (F32IN) {
        // 64 rows x 64 f32 cols, convert to f16
#pragma unroll
        for (int it = 0; it < 4; ++it) {
            int u = it * 256 + t, row = u >> 4, k = (u & 15) * 4, gr = rbase + row;
            f32x4 v = {};
            if (gr < NE) v = *(const f32x4*)(in0f + (size_t)gr * 64 + k);
            f16x4 o = {(f16)v[0], (f16)v[1], (f16)v[2], (f16)v[3]};
            *(f16x4*)(Abuf + row * SA + k) = o;
        }
    } else if constexpr (K1 == 64) {
#pragma unroll
        for (int it = 0; it < 2; ++it) {
            int u = it * 256 + t, row = u >> 3, k = (u & 7) * 8, gr = rbase + row;
            half8 v = {};
            if (gr < NE) v = *(const half8*)(in0 + (size_t)gr * 64 + k);
            *(half8*)(Abuf + row * SA + k) = v;
        }
    } else {
#pragma unroll
        for (int it = 0; it < 4; ++it) {
            int u = it * 256 + t, row = u >> 4, k = (u & 15) * 8, gr = rbase + row;
            half8 v = {};
            if (gr < NE) v = *(const half8*)(in0 + (size_t)gr * 128 + k);
            *(half8*)(Abuf + row * SA + k) = v;
        }
    }
    if constexpr (MSG) {
#pragma unroll
        for (int it = 0; it < 4; ++it) {
            int u = it * 256 + t, row = u >> 4, k = (u & 15) * 8, gr = rbase + row;
            half8 v = {};
            if (gr < NE) v = *(const half8*)(in1 + (size_t)gr * 128 + k);
            *(half8*)(Abuf + row * SA + 128 + k) = v;
        }
    }
    __syncthreads();

    // ---- GEMM1: [64 x K1] @ [K1 x 128] + b1, relu -> Hbuf (weights dbuf'd)
    f32x4 acc[4][2];
    {
        float bb0 = b1v[n0 + mn], bb1 = b1v[n0 + 16 + mn];
#pragma unroll
        for (int mt = 0; mt < 4; ++mt) {
            acc[mt][0] = (f32x4){bb0, bb0, bb0, bb0};
            acc[mt][1] = (f32x4){bb1, bb1, bb1, bb1};
        }
    }
    {
        const f16* wrA = w1t + (size_t)(n0 + mn) * w1s + quad * 8;
        const f16* wrB = w1t + (size_t)(n0 + 16 + mn) * w1s + quad * 8;
        half8 wA = *(const half8*)(wrA);
        half8 wB = *(const half8*)(wrB);
#pragma unroll
        for (int kc = 0; kc < NKC; ++kc) {
            half8 wAn = {}, wBn = {};
            if (kc + 1 < NKC) {
                wAn = *(const half8*)(wrA + (kc + 1) * 32);
                wBn = *(const half8*)(wrB + (kc + 1) * 32);
            }
            half8 af[4];
#pragma unroll
            for (int mt = 0; mt < 4; ++mt)
                af[mt] = *(const half8*)(Abuf + (mt * 16 + mn) * SA + kc * 32 + quad * 8);
#pragma unroll
            for (int mt = 0; mt < 4; ++mt) {
                acc[mt][0] = __builtin_amdgcn_mfma_f32_16x16x32_f16(af[mt], wA, acc[mt][0], 0, 0, 0);
                acc[mt][1] = __builtin_amdgcn_mfma_f32_16x16x32_f16(af[mt], wB, acc[mt][1], 0, 0, 0);
            }
            wA = wAn; wB = wBn;
        }
    }
    __syncthreads();  // A reads done before aliased Hbuf writes
#pragma unroll
    for (int mt = 0; mt < 4; ++mt)
#pragma unroll
        for (int nt = 0; nt < 2; ++nt)
#pragma unroll
            for (int r = 0; r < 4; ++r)
                Hbuf[(mt * 16 + quad * 4 + r) * SH + n0 + nt * 16 + mn] =
                    (f16)fmaxf(acc[mt][nt][r], 0.f);
    __syncthreads();

    // ---- GEMM2: [64x128]@[128x128] + b2 (+relu) -> Ebuf (weights dbuf'd)
    {
        float bb0 = b2v[n0 + mn], bb1 = b2v[n0 + 16 + mn];
#pragma unroll
        for (int mt = 0; mt < 4; ++mt) {
            acc[mt][0] = (f32x4){bb0, bb0, bb0, bb0};
            acc[mt][1] = (f32x4){bb1, bb1, bb1, bb1};
        }
    }
    {
        const f16* wrA = w2t + (size_t)(n0 + mn) * 128 + quad * 8;
        const f16* wrB = w2t + (size_t)(n0 + 16 + mn) * 128 + quad * 8;
        half8 wA = *(const half8*)(wrA);
        half8 wB = *(const half8*)(wrB);
#pragma unroll
        for (int kc = 0; kc < 4; ++kc) {
            half8 wAn = {}, wBn = {};
            if (kc + 1 < 4) {
                wAn = *(const half8*)(wrA + (kc + 1) * 32);
                wBn = *(const half8*)(wrB + (kc + 1) * 32);
            }
            half8 af[4];
#pragma unroll
            for (int mt = 0; mt < 4; ++mt)
                af[mt] = *(const half8*)(Hbuf + (mt * 16 + mn) * SH + kc * 32 + quad * 8);
#pragma unroll
            for (int mt = 0; mt < 4; ++mt) {
                acc[mt][0] = __builtin_amdgcn_mfma_f32_16x16x32_f16(af[mt], wA, acc[mt][0], 0, 0, 0);
                acc[mt][1] = __builtin_amdgcn_mfma_f32_16x16x32_f16(af[mt], wB, acc[mt][1], 0, 0, 0);
            }
            wA = wAn; wB = wBn;
        }
    }
#pragma unroll
    for (int mt = 0; mt < 4; ++mt)
#pragma unroll
        for (int nt = 0; nt < 2; ++nt)
#pragma unroll
            for (int r = 0; r < 4; ++r) {
                float v = acc[mt][nt][r];
                if (reluOut) v = fmaxf(v, 0.f);
                Ebuf[(mt * 16 + quad * 4 + r) * SH + n0 + nt * 16 + mn] = (f16)v;
            }
    __syncthreads();  // Ebuf ready

    // ---- vectorized e' store from Ebuf (skipped when dead, e.g. last layer)
    if (oute) {
#pragma unroll
        for (int it = 0; it < 4; ++it) {
            int u = it * 256 + t, row = u >> 4, k = (u & 15) * 8, gr = rbase + row;
            if (gr < NE) {
                half8 v = *(const half8*)(Ebuf + row * SH + k);
                *(half8*)(oute + (size_t)gr * 128 + k) = v;
            }
        }
    }

    // ---- fused P/Q GEMM: one pass over Ebuf fragments feeds both weight sets
    f32x4 aQ[4][2];
    {
        float bb0 = bPp[n0 + mn], bb1 = bPp[n0 + 16 + mn];
#pragma unroll
        for (int mt = 0; mt < 4; ++mt) {
            acc[mt][0] = (f32x4){bb0, bb0, bb0, bb0};
            acc[mt][1] = (f32x4){bb1, bb1, bb1, bb1};
            aQ[mt][0] = (f32x4){0.f, 0.f, 0.f, 0.f};
            aQ[mt][1] = (f32x4){0.f, 0.f, 0.f, 0.f};
        }
    }
#pragma unroll
    for (int kc = 0; kc < 4; ++kc) {
        half8 wPA = *(const half8*)(wpq + (size_t)(n0 + mn) * 128 + kc * 32 + quad * 8);
        half8 wPB = *(const half8*)(wpq + (size_t)(n0 + 16 + mn) * 128 + kc * 32 + quad * 8);
        half8 wQA = *(const half8*)(wpq + 16384 + (size_t)(n0 + mn) * 128 + kc * 32 + quad * 8);
        half8 wQB = *(const half8*)(wpq + 16384 + (size_t)(n0 + 16 + mn) * 128 + kc * 32 + quad * 8);
        half8 af[4];
#pragma unroll
        for (int mt = 0; mt < 4; ++mt)
            af[mt] = *(const half8*)(Ebuf + (mt * 16 + mn) * SH + kc * 32 + quad * 8);
#pragma unroll
        for (int mt = 0; mt < 4; ++mt) {
            acc[mt][0] = __builtin_amdgcn_mfma_f32_16x16x32_f16(af[mt], wPA, acc[mt][0], 0, 0, 0);
            acc[mt][1] = __builtin_amdgcn_mfma_f32_16x16x32_f16(af[mt], wPB, acc[mt][1], 0, 0, 0);
            aQ[mt][0] = __builtin_amdgcn_mfma_f32_16x16x32_f16(af[mt], wQA, aQ[mt][0], 0, 0, 0);
            aQ[mt][1] = __builtin_amdgcn_mfma_f32_16x16x32_f16(af[mt], wQB, aQ[mt][1], 0, 0, 0);
        }
    }
    // channel-packed store: group = wave*2+nt (uniform), within-group ch = mn
#pragma unroll
    for (int mt = 0; mt < 4; ++mt)
#pragma unroll
        for (int nt = 0; nt < 2; ++nt) {
            const size_t gbase = (size_t)(wave * 2 + nt) * NE;
#pragma unroll
            for (int r = 0; r < 4; ++r) {
                int gr = rbase + mt * 16 + quad * 4 + r;
                if (gr < NE) {
                    Pout[(gbase + gr) * 16 + mn] = (f16)acc[mt][nt][r];
                    Qout[(gbase + gr) * 16 + mn] = (f16)aQ[mt][nt][r];
                }
            }
        }
}

// one predictor tile: h1=relu(P1[i]+Q1[j]); h2=relu(h1@W2+b2); logit=h2@w3+b3; sigmoid
// P1/Q1 are channel-packed [8][NE][16].
__device__ __forceinline__ void pred_tile(const KP& p, char* SMEM, float* w3s,
                                          float* psum, int tile, float b3v) {
    constexpr int SA = 136, SO = 133;
    f16* Abuf = (f16*)SMEM;
    float* Obuf = (float*)SMEM;
    const int t = threadIdx.x, lane = t & 63, wave = t >> 6;
    const int quad = lane >> 4, mn = lane & 15, n0 = wave * 32;
    const int rbase = tile << 6;
    // ---- gather staging: all indices first (one latency hop), then all 8 row
    // loads in flight (second hop), then combine+store.
    {
        int ii[4], jj[4];
        bool ok[4];
#pragma unroll
        for (int it = 0; it < 4; ++it) {
            int u = it * 256 + t, row = u >> 4, gr = rbase + row;
            ok[it] = gr < NC;
            int g2 = ok[it] ? gr : 0;
            ii[it] = p.cand_i[g2];
            jj[it] = p.cand_j[g2];
        }
        half8 av[4], bv[4];
#pragma unroll
        for (int it = 0; it < 4; ++it) {
            int u = it * 256 + t, k = (u & 15) * 8;   // k = ch base (0,8,...,120)
            const size_t po = ((size_t)(k >> 4) * NE) * 16 + (k & 15);
            av[it] = *(const half8*)(p.P1 + po + (size_t)ii[it] * 16);
            bv[it] = *(const half8*)(p.Q1 + po + (size_t)jj[it] * 16);
        }
#pragma unroll
        for (int it = 0; it < 4; ++it) {
            int u = it * 256 + t, row = u >> 4, k = (u & 15) * 8;
            half8 v = {};
            if (ok[it]) {
#pragma unroll
                for (int x = 0; x < 8; ++x)
                    v[x] = (f16)fmaxf((float)av[it][x] + (float)bv[it][x], 0.f);
            }
            *(half8*)(Abuf + row * SA + k) = v;
        }
    }
    __syncthreads();
    f32x4 acc[4][2];
    {
        float bb0 = p.pred_b2[n0 + mn], bb1 = p.pred_b2[n0 + 16 + mn];
#pragma unroll
        for (int mt = 0; mt < 4; ++mt) {
            acc[mt][0] = (f32x4){bb0, bb0, bb0, bb0};
            acc[mt][1] = (f32x4){bb1, bb1, bb1, bb1};
        }
    }
    {
        const f16* wrA = p.wt + OFF_PREDW2 + (size_t)(n0 + mn) * 128 + quad * 8;
        const f16* wrB = p.wt + OFF_PREDW2 + (size_t)(n0 + 16 + mn) * 128 + quad * 8;
        half8 wA = *(const half8*)(wrA);
        half8 wB = *(const half8*)(wrB);
#pragma unroll
        for (int kc = 0; kc < 4; ++kc) {
            half8 wAn = {}, wBn = {};
            if (kc + 1 < 4) {
                wAn = *(const half8*)(wrA + (kc + 1) * 32);
                wBn = *(const half8*)(wrB + (kc + 1) * 32);
            }
            half8 af[4];
#pragma unroll
            for (int mt = 0; mt < 4; ++mt)
                af[mt] = *(const half8*)(Abuf + (mt * 16 + mn) * SA + kc * 32 + quad * 8);
#pragma unroll
            for (int mt = 0; mt < 4; ++mt) {
                acc[mt][0] = __builtin_amdgcn_mfma_f32_16x16x32_f16(af[mt], wA, acc[mt][0], 0, 0, 0);
                acc[mt][1] = __builtin_amdgcn_mfma_f32_16x16x32_f16(af[mt], wB, acc[mt][1], 0, 0, 0);
            }
            wA = wAn; wB = wBn;
        }
    }
    __syncthreads();  // Abuf reads done before aliased Obuf writes
#pragma unroll
    for (int mt = 0; mt < 4; ++mt)
#pragma unroll
        for (int nt = 0; nt < 2; ++nt)
#pragma unroll
            for (int r = 0; r < 4; ++r)
                Obuf[(mt * 16 + quad * 4 + r) * SO + n0 + nt * 16 + mn] =
                    fmaxf(acc[mt][nt][r], 0.f);
    __syncthreads();
    {
        int row = t & 63, q4 = t >> 6;
        float s = 0.f;
#pragma unroll
        for (int i = 0; i < 32; ++i)
            s += Obuf[row * SO + q4 * 32 + i] * w3s[q4 * 32 + i];
        psum[t] = s;
    }
    __syncthreads();
    if (t < 64) {
        int gr = rbase + t;
        if (gr < NC) {
            float lg = psum[t] + psum[t + 64] + psum[t + 128] + psum[t + 192] + b3v;
            p.outL[gr] = lg;
            p.outP[gr] = 1.f / (1.f + expf(-lg));
        }
    }
}

__device__ __forceinline__ void upd_layer_ptrs(const KP& p, int l,
    const f16*& ein, f16*& eout, const f16*& Pin, const f16*& Qin,
    f16*& Pout, f16*& Qout, const f16*& wpq, const float*& bP) {
    ein = (l & 1) ? p.eB : p.eA;
    eout = (l == 2) ? nullptr : ((l & 1) ? p.eA : p.eB);  // l=2 e' is dead
    Pin = (l & 1) ? p.P1 : p.P0;
    Qin = (l & 1) ? p.Q1 : p.Q0;
    Pout = (l & 1) ? p.P0 : p.P1;
    Qout = (l & 1) ? p.Q0 : p.Q1;
    wpq = (l < 2) ? (p.wt + OFF_MSGPQ + (l + 1) * 32768) : (p.wt + OFF_PREDPQ);
    bP = (l < 2) ? (p.msg_b1 + (l + 1) * 128) : p.pred_b1;
}

// ---------------- plain launches ----------------
__global__ void k_prep(KP p) {
    int gid = blockIdx.x * 256 + threadIdx.x;
    if (gid < PTOT) prep_item(p, gid);
}
// encoder + PQ0 tile (raw f32 input), then grid-stride degseg over NA
__global__ __launch_bounds__(256, 4) void k_encdeg(KP p) {
    __shared__ __align__(16) char SMEM[34816];
    do_tile<64, false, true>(SMEM, blockIdx.x, nullptr, p.edge_features, nullptr,
                             p.wt + OFF_ENC1, 64, p.enc_b1, p.wt + OFF_ENC2, p.enc_b2, false,
                             p.eA, p.wt + OFF_MSGPQ, p.msg_b1, p.P0, p.Q0);
    const int nthr = gridDim.x * 256;
    for (int i = blockIdx.x * 256 + threadIdx.x; i < NA; i += nthr) degseg_item(p, i);
}

// XCD-sharded aggregation over channel-packed P/Q.
// Block b handles channel group (b & 7); consecutive blockIdx round-robin
// across XCDs, so all blocks of group g land on XCD g -> per-XCD gather
// working set = NE*16ch*2B = 1.6 MB (L2-resident).
// 2 threads per dst (8 channels each); plain cached loads; TLP hides latency.
__global__ __launch_bounds__(256, 8) void k_agg(KP p, int l) {
    const f16* __restrict__ Pin = (l & 1) ? p.P1 : p.P0;
    const f16* __restrict__ Qin = (l & 1) ? p.Q1 : p.Q0;
    const int bg = blockIdx.x & 7;      // channel group == XCD
    const int dt = blockIdx.x >> 3;
    const int t = threadIdx.x;
    const int dst = dt * 128 + (t >> 1);
    const int hf = t & 1;               // which 8-ch half of the 16-ch group
    if (dst >= NE) return;
    const int s = p.segStart[dst];
    const int deg = p.segEnd[dst] - s;
    const bool iso = (deg == 0);
    const int d1 = iso ? 1 : deg;
    const f16* __restrict__ Qg = Qin + (size_t)bg * NE * 16 + hf * 8;
    half8 pv = *(const half8*)(Pin + ((size_t)bg * NE + dst) * 16 + hf * 8);
    float x[8] = {0.f, 0.f, 0.f, 0.f, 0.f, 0.f, 0.f, 0.f};
    // 1-deep prefetch: next neighbor's Q row in flight while consuming current
    int i0 = iso ? dst : p.adj_src[s];
    half8 q = *(const half8*)(Qg + (size_t)i0 * 16);
    for (int j = 0; j < d1; ++j) {
        half8 qn = q;
        if (j + 1 < d1) {
            int ni = p.adj_src[s + j + 1];
            qn = *(const half8*)(Qg + (size_t)ni * 16);
        }
#pragma unroll
        for (int c = 0; c < 8; ++c)
            x[c] += fmaxf((float)pv[c] + (float)q[c], 0.f);
        q = qn;
    }
    const float sc = 1.f / (float)d1;
    half8 o;
#pragma unroll
    for (int c = 0; c < 8; ++c) o[c] = (f16)(x[c] * sc);
    *(half8*)(p.mbuf + (size_t)dst * 128 + bg * 16 + hf * 8) = o;
}

// layer update: streaming MSG from mbuf + update MLP + packed P/Q projections
__global__ __launch_bounds__(256, 4) void k_layer(KP p, int l) {
    __shared__ __align__(16) char SMEM[34816];
    const f16 *ein, *Pin, *Qin, *wpq;
    f16 *eout, *Pout, *Qout;
    const float* bP;
    upd_layer_ptrs(p, l, ein, eout, Pin, Qin, Pout, Qout, wpq, bP);
    do_tile<256, true, false>(SMEM, blockIdx.x, ein, nullptr, p.mbuf,
                              p.wt + OFF_UPD1 + l * 32768, 256, p.fbias + l * 128,
                              p.wt + OFF_UPD2 + l * 16384, p.upd_b2 + l * 128, true,
                              eout, wpq, bP, Pout, Qout);
}
__global__ __launch_bounds__(256, 4) void k_pred(KP p) {
    __shared__ __align__(16) char SMEM[34816];
    __shared__ float w3s[128];
    __shared__ float psum[256];
    if (threadIdx.x < 128) w3s[threadIdx.x] = p.pred_W3[threadIdx.x];
    float b3v = p.pred_b3[0];
    pred_tile(p, SMEM, w3s, psum, blockIdx.x, b3v);
}

// ---------------- host ----------------
extern "C" void kernel_launch(void* const* d_in, const int* in_sizes, int n_in,
                              void* d_out, int out_size, void* d_ws, size_t ws_size,
                              hipStream_t stream) {
    KP p;
    p.edge_features = (const float*)d_in[0];
    p.adj_dst = (const int*)d_in[1];
    p.adj_src = (const int*)d_in[2];
    p.cand_i = (const int*)d_in[3];
    p.cand_j = (const int*)d_in[4];
    const float* enc_W1 = (const float*)d_in[5];
    p.enc_b1 = (const float*)d_in[6];
    const float* enc_W2 = (const float*)d_in[7];
    p.enc_b2 = (const float*)d_in[8];
    const float* msg_W1 = (const float*)d_in[9];
    p.msg_b1 = (const float*)d_in[10];
    p.msg_W2 = (const float*)d_in[11];
    p.msg_b2 = (const float*)d_in[12];
    p.upd_W1 = (const float*)d_in[13];
    p.upd_b1 = (const float*)d_in[14];
    const float* upd_W2 = (const float*)d_in[15];
    p.upd_b2 = (const float*)d_in[16];
    const float* pred_W1 = (const float*)d_in[17];
    p.pred_b1 = (const float*)d_in[18];
    const float* pred_W2 = (const float*)d_in[19];
    p.pred_b2 = (const float*)d_in[20];
    p.pred_W3 = (const float*)d_in[21];
    p.pred_b3 = (const float*)d_in[22];

    char* ws = (char*)d_ws;
    size_t off = 0;
    auto alloc = [&](size_t bytes) -> void* {
        void* q = ws + off;
        off = (off + bytes + 255) & ~(size_t)255;
        return q;
    };
    p.wt = (f16*)alloc((size_t)TOTAL_WT * 2);
    p.fbias = (float*)alloc(3 * 128 * 4);
    p.eA = (f16*)alloc((size_t)NE * 128 * 2);
    p.eB = (f16*)alloc((size_t)NE * 128 * 2);
    p.P0 = (f16*)alloc((size_t)NE * 128 * 2);
    p.Q0 = (f16*)alloc((size_t)NE * 128 * 2);
    p.P1 = (f16*)alloc((size_t)NE * 128 * 2);
    p.Q1 = (f16*)alloc((size_t)NE * 128 * 2);
    p.mbuf = (f16*)alloc((size_t)NE * 128 * 2);
    p.segStart = (int*)alloc((size_t)NE * 4);
    p.segEnd = (int*)alloc((size_t)NE * 4);
    p.outP = (float*)d_out;
    p.outL = (float*)d_out + NC;

    int idx = 0, c = 0;
    auto addj = [&](const float* s, int K, int o, int st) {
        p.wsrc[idx] = s; p.wK[idx] = K; p.wOff[idx] = o;
        p.wStr[idx] = st; p.wCum[idx] = c;
        c += K * 128; idx++;
    };
    addj(enc_W1, 64, OFF_ENC1, 64);
    addj(enc_W2, 128, OFF_ENC2, 128);
    for (int l = 0; l < 3; ++l) addj(msg_W1 + (size_t)l * 32768, 128, OFF_MSGPQ + l * 32768, 128);
    for (int l = 0; l < 3; ++l) addj(msg_W1 + (size_t)l * 32768 + 16384, 128, OFF_MSGPQ + l * 32768 + 16384, 128);
    for (int l = 0; l < 3; ++l) addj(p.upd_W1 + (size_t)l * 32768, 128, OFF_UPD1 + l * 32768, 256);
    for (int l = 0; l < 3; ++l) addj(upd_W2 + (size_t)l * 16384, 128, OFF_UPD2 + l * 16384, 128);
    addj(pred_W1, 128, OFF_PREDPQ, 128);
    addj(pred_W1 + 16384, 128, OFF_PREDPQ + 16384, 128);
    addj(pred_W2, 128, OFF_PREDW2, 128);
    for (int i = idx; i <= 20; ++i) p.wCum[i] = c;  // c == 270336 == R_WT

    const int tilesNE = (NE + 63) / 64;          // 782
    const int dtAGG = (NE + 127) / 128;          // 391
    const int tilesAGG = dtAGG * 8;              // 3128 (x8 channel groups)
    const int tilesNC = (NC + 63) / 64;          // 1563
    k_prep<<<(PTOT + 255) / 256, 256, 0, stream>>>(p);
    k_encdeg<<<tilesNE, 256, 0, stream>>>(p);
    for (int l = 0; l < 3; ++l) {
        k_agg<<<tilesAGG, 256, 0, stream>>>(p, l);
        k_layer<<<tilesNE, 256, 0, stream>>>(p, l);
    }
    k_pred<<<tilesNC, 256, 0, stream>>>(p);

    (void)in_sizes; (void)n_in; (void)out_size; (void)ws_size;
}

// Round 9
// 350.719 us; speedup vs baseline: 1.1877x; 1.1877x over previous
//
#include <hip/hip_runtime.h>
#include <hip/hip_bf16.h>

#define NE 50000
#define NA 800000
#define NC 100000

typedef _Float16 f16;
typedef f16 half8 __attribute__((ext_vector_type(8)));
typedef f16 f16x2 __attribute__((ext_vector_type(2)));
typedef f16 f16x4 __attribute__((ext_vector_type(4)));
typedef float f32x4 __attribute__((ext_vector_type(4)));

// f16-element offsets inside the converted-weight arena
#define OFF_ENC1 0
#define OFF_ENC2 8192
#define OFF_MSGPQ 24576    // 3 layers x 32768 (P block 16384 + Q block 16384)
#define OFF_UPD1 122880    // 3 layers x 32768, fused layout [n][256]
#define OFF_UPD2 221184    // 3 layers x 16384
#define OFF_PREDPQ 270336  // 32768
#define OFF_PREDW2 303104  // 16384
#define TOTAL_WT 319488

#define R_FUSE 49536       // 3*129 groups x 128 threads
#define R_WT 270336
#define R_Z 50000
#define PTOT (R_FUSE + R_WT + R_Z)

struct KP {
    const float* edge_features;
    const int *adj_dst, *adj_src, *cand_i, *cand_j;
    const float *enc_b1, *enc_b2;
    const float *msg_b1, *msg_W2, *msg_b2;
    const float *upd_W1, *upd_b1, *upd_b2;
    const float *pred_b1, *pred_b2, *pred_W3, *pred_b3;
    f16* wt;
    float* fbias;
    f16 *eA, *eB, *P0, *Q0, *P1, *Q1;
    int *segStart, *segEnd;
    float *outP, *outL;
    const float* wsrc[20];
    int wK[20], wOff[20], wStr[20], wCum[21];
};

// ---------------- shared device bodies ----------------

__device__ __forceinline__ void prep_item(const KP& p, int gid) {
    if (gid < R_FUSE) {
        // fused W2U = msg_W2 @ upd_W1[128:256] and fbias; coalesced per 128-group
        int g = gid >> 7, n = gid & 127;
        int l = g / 129, kk = g % 129;
        const float* U1b = p.upd_W1 + (size_t)l * 32768 + 16384;
        if (kk < 128) {
            const float* w2row = p.msg_W2 + (size_t)l * 16384 + (size_t)kk * 128;
            float s = 0.f;
            for (int m = 0; m < 128; ++m) s += w2row[m] * U1b[m * 128 + n];
            p.wt[OFF_UPD1 + l * 32768 + n * 256 + 128 + kk] = (f16)s;
        } else {
            const float* b2 = p.msg_b2 + l * 128;
            float s = p.upd_b1[l * 128 + n];
            for (int m = 0; m < 128; ++m) s += b2[m] * U1b[m * 128 + n];
            p.fbias[l * 128 + n] = s;
        }
    } else if (gid < R_FUSE + R_WT) {
        int e = gid - R_FUSE;
        int j = 0;
#pragma unroll
        for (int i = 1; i < 20; ++i) j += (e >= p.wCum[i]) ? 1 : 0;
        int r = e - p.wCum[j];
        int K = p.wK[j];
        int k = r % K, n = r / K;
        p.wt[p.wOff[j] + n * p.wStr[j] + k] = (f16)p.wsrc[j][(size_t)k * 128 + n];
    } else if (gid < PTOT) {
        int z = gid - (R_FUSE + R_WT);
        p.segStart[z] = 0;
        p.segEnd[z] = 0;
    }
}

__device__ __forceinline__ void degseg_item(const KP& p, int i) {
    int d = p.adj_dst[i];
    if (i == 0 || p.adj_dst[i - 1] != d) p.segStart[d] = i;
    if (i == NA - 1 || p.adj_dst[i + 1] != d) p.segEnd[d] = i + 1;
}

// one 64-row tile: [in-tile gather agg]? -> GEMM1(K1) -> relu -> GEMM2 -> e'
// -> fused P/Q GEMM.
// AGG: gather right half of A via quarter-wave-per-dst shfl-broadcast gather.
//      CHANNEL-SPLIT into 2 passes of 64 channels (halves the per-pass Q
//      working set -> better L2 hit) with PLAIN cached loads/stores
//      (round-7's nt-hints caused write amplification; removed).
//      Line-visit count unchanged: each pass reads a full 128B line per row.
// F32IN: stage A from raw f32 in0f (convert on the fly) instead of f16 in0.
template <int K1, bool AGG, bool F32IN>
__device__ __forceinline__ void do_tile(
    char* SMEM, int tile, const f16* __restrict__ in0, const float* __restrict__ in0f,
    const f16* __restrict__ Pin, const f16* __restrict__ Qin,
    const int* __restrict__ adj_src, const int* __restrict__ segStart,
    const int* __restrict__ segEnd,
    const f16* __restrict__ w1t, const int w1s, const float* __restrict__ b1v,
    const f16* __restrict__ w2t, const float* __restrict__ b2v, const bool reluOut,
    f16* __restrict__ oute,
    const f16* __restrict__ wpq, const float* __restrict__ bPp,
    f16* __restrict__ Pout, f16* __restrict__ Qout) {
    constexpr int SA = K1 + 8;   // f16 stride
    constexpr int SH = 136;      // f16 stride for H/E
    constexpr int NKC = K1 / 32;
    f16* Abuf = (f16*)SMEM;
    f16* Hbuf = (f16*)SMEM;                  // aliases Abuf low (dead after GEMM1)
    f16* Ebuf = (f16*)(SMEM + 17408);        // after Hbuf; overlaps dead Abuf top
    const int t = threadIdx.x, lane = t & 63, wave = t >> 6;
    const int quad = lane >> 4, mn = lane & 15, n0 = wave * 32;
    const int rbase = tile << 6;

    // ---- in-tile gather agg first (channel-split, 2 passes; plain loads)
    if constexpr (AGG) {
        const int cl = mn;             // channel-lane 0..15
        const int qb = quad << 4;      // quarter base lane within wave
        // preload all 4 groups' indices ONCE (coalesced lane-parallel + shfl)
        int s_[4], deg_[4], i0_[4], i1_[4], i2_[4];
#pragma unroll
        for (int g = 0; g < 4; ++g) {
            const int dst = rbase + wave * 16 + g * 4 + quad;
            int s = 0, de = 0;
            if (dst < NE) { s = segStart[dst]; de = segEnd[dst] - s; }
            s_[g] = s; deg_[g] = de;
            i0_[g] = (cl < de) ? adj_src[s + cl] : 0;
            i1_[g] = (cl + 16 < de) ? adj_src[s + cl + 16] : 0;
            i2_[g] = (cl + 32 < de) ? adj_src[s + cl + 32] : 0;
        }
#pragma unroll
        for (int ph = 0; ph < 2; ++ph) {
            const int coff = ph * 64 + cl * 4;  // this pass: 64 channels, 4/lane
#pragma unroll
            for (int g = 0; g < 4; ++g) {
                const int drow = wave * 16 + g * 4 + quad;
                const int dst = rbase + drow;
                if (dst < NE) {
                    const int deg = deg_[g];
                    const bool iso = (deg == 0);
                    const int d1 = iso ? 1 : deg;
                    f16x4 pv = *(const f16x4*)(Pin + (size_t)dst * 128 + coff);
                    float x[4] = {0.f, 0.f, 0.f, 0.f};
                    const int nb = min((d1 + 7) >> 3, 6);
                    f16x4 qA[8], qB[8];  // 2-slot pipeline, static names

                    auto issue = [&](int b, f16x4* qq) {
                        int ireg = (b < 2) ? i0_[g] : (b < 4) ? i1_[g] : i2_[g];
                        const int base = (b & 1) * 8;
#pragma unroll
                        for (int u = 0; u < 8; ++u) {
                            int sj = __shfl(ireg, qb + base + u, 64);
                            int j = b * 8 + u;
                            int idx = iso ? dst : ((j < d1) ? sj : dst);
                            qq[u] = *(const f16x4*)(Qin + (size_t)idx * 128 + coff);
                        }
                    };
                    auto consume = [&](int b, f16x4* qq) {
#pragma unroll
                        for (int u = 0; u < 8; ++u) {
                            if (b * 8 + u < d1) {
#pragma unroll
                                for (int c = 0; c < 4; ++c)
                                    x[c] += fmaxf((float)pv[c] + (float)qq[u][c], 0.f);
                            }
                        }
                    };
                    issue(0, qA);
#pragma unroll
                    for (int b = 0; b < 6; ++b) {
                        if (b < nb) {
                            f16x4* cur = (b & 1) ? qB : qA;
                            f16x4* nxt = (b & 1) ? qA : qB;
                            if (b + 1 < nb) issue(b + 1, nxt);
                            consume(b, cur);
                        }
                    }
                    // overflow tail (deg > 48): statistically near-impossible
                    for (int j = 48; j < d1; ++j) {
                        int idx = adj_src[s_[g] + j];
                        f16x4 qj = *(const f16x4*)(Qin + (size_t)idx * 128 + coff);
#pragma unroll
                        for (int c = 0; c < 4; ++c)
                            x[c] += fmaxf((float)pv[c] + (float)qj[c], 0.f);
                    }
                    const float sc = 1.f / (float)d1;
                    f16x4 o;
#pragma unroll
                    for (int c = 0; c < 4; ++c) o[c] = (f16)(x[c] * sc);
                    *(f16x4*)(Abuf + drow * SA + 128 + coff) = o;
                }
            }
        }
    }

    // ---- stage A-tile left half (or all of it for K1==64) from in0/in0f
    if constexpr (F32IN) {
        // 64 rows x 64 f32 cols, convert to f16
#pragma unroll
        for (int it = 0; it < 4; ++it) {
            int u = it * 256 + t, row = u >> 4, k = (u & 15) * 4, gr = rbase + row;
            f32x4 v = {};
            if (gr < NE) v = *(const f32x4*)(in0f + (size_t)gr * 64 + k);
            f16x4 o = {(f16)v[0], (f16)v[1], (f16)v[2], (f16)v[3]};
            *(f16x4*)(Abuf + row * SA + k) = o;
        }
    } else if constexpr (K1 == 64) {
#pragma unroll
        for (int it = 0; it < 2; ++it) {
            int u = it * 256 + t, row = u >> 3, k = (u & 7) * 8, gr = rbase + row;
            half8 v = {};
            if (gr < NE) v = *(const half8*)(in0 + (size_t)gr * 64 + k);
            *(half8*)(Abuf + row * SA + k) = v;
        }
    } else {
#pragma unroll
        for (int it = 0; it < 4; ++it) {
            int u = it * 256 + t, row = u >> 4, k = (u & 15) * 8, gr = rbase + row;
            half8 v = {};
            if (gr < NE) v = *(const half8*)(in0 + (size_t)gr * 128 + k);
            *(half8*)(Abuf + row * SA + k) = v;
        }
    }
    __syncthreads();

    // ---- GEMM1: [64 x K1] @ [K1 x 128] + b1, relu -> Hbuf (weights dbuf'd)
    f32x4 acc[4][2];
    {
        float bb0 = b1v[n0 + mn], bb1 = b1v[n0 + 16 + mn];
#pragma unroll
        for (int mt = 0; mt < 4; ++mt) {
            acc[mt][0] = (f32x4){bb0, bb0, bb0, bb0};
            acc[mt][1] = (f32x4){bb1, bb1, bb1, bb1};
        }
    }
    {
        const f16* wrA = w1t + (size_t)(n0 + mn) * w1s + quad * 8;
        const f16* wrB = w1t + (size_t)(n0 + 16 + mn) * w1s + quad * 8;
        half8 wA = *(const half8*)(wrA);
        half8 wB = *(const half8*)(wrB);
#pragma unroll
        for (int kc = 0; kc < NKC; ++kc) {
            half8 wAn = {}, wBn = {};
            if (kc + 1 < NKC) {
                wAn = *(const half8*)(wrA + (kc + 1) * 32);
                wBn = *(const half8*)(wrB + (kc + 1) * 32);
            }
            half8 af[4];
#pragma unroll
            for (int mt = 0; mt < 4; ++mt)
                af[mt] = *(const half8*)(Abuf + (mt * 16 + mn) * SA + kc * 32 + quad * 8);
#pragma unroll
            for (int mt = 0; mt < 4; ++mt) {
                acc[mt][0] = __builtin_amdgcn_mfma_f32_16x16x32_f16(af[mt], wA, acc[mt][0], 0, 0, 0);
                acc[mt][1] = __builtin_amdgcn_mfma_f32_16x16x32_f16(af[mt], wB, acc[mt][1], 0, 0, 0);
            }
            wA = wAn; wB = wBn;
        }
    }
    __syncthreads();  // A reads done before aliased Hbuf writes
#pragma unroll
    for (int mt = 0; mt < 4; ++mt)
#pragma unroll
        for (int nt = 0; nt < 2; ++nt)
#pragma unroll
            for (int r = 0; r < 4; ++r)
                Hbuf[(mt * 16 + quad * 4 + r) * SH + n0 + nt * 16 + mn] =
                    (f16)fmaxf(acc[mt][nt][r], 0.f);
    __syncthreads();

    // ---- GEMM2: [64x128]@[128x128] + b2 (+relu) -> Ebuf (weights dbuf'd)
    {
        float bb0 = b2v[n0 + mn], bb1 = b2v[n0 + 16 + mn];
#pragma unroll
        for (int mt = 0; mt < 4; ++mt) {
            acc[mt][0] = (f32x4){bb0, bb0, bb0, bb0};
            acc[mt][1] = (f32x4){bb1, bb1, bb1, bb1};
        }
    }
    {
        const f16* wrA = w2t + (size_t)(n0 + mn) * 128 + quad * 8;
        const f16* wrB = w2t + (size_t)(n0 + 16 + mn) * 128 + quad * 8;
        half8 wA = *(const half8*)(wrA);
        half8 wB = *(const half8*)(wrB);
#pragma unroll
        for (int kc = 0; kc < 4; ++kc) {
            half8 wAn = {}, wBn = {};
            if (kc + 1 < 4) {
                wAn = *(const half8*)(wrA + (kc + 1) * 32);
                wBn = *(const half8*)(wrB + (kc + 1) * 32);
            }
            half8 af[4];
#pragma unroll
            for (int mt = 0; mt < 4; ++mt)
                af[mt] = *(const half8*)(Hbuf + (mt * 16 + mn) * SH + kc * 32 + quad * 8);
#pragma unroll
            for (int mt = 0; mt < 4; ++mt) {
                acc[mt][0] = __builtin_amdgcn_mfma_f32_16x16x32_f16(af[mt], wA, acc[mt][0], 0, 0, 0);
                acc[mt][1] = __builtin_amdgcn_mfma_f32_16x16x32_f16(af[mt], wB, acc[mt][1], 0, 0, 0);
            }
            wA = wAn; wB = wBn;
        }
    }
#pragma unroll
    for (int mt = 0; mt < 4; ++mt)
#pragma unroll
        for (int nt = 0; nt < 2; ++nt)
#pragma unroll
            for (int r = 0; r < 4; ++r) {
                float v = acc[mt][nt][r];
                if (reluOut) v = fmaxf(v, 0.f);
                Ebuf[(mt * 16 + quad * 4 + r) * SH + n0 + nt * 16 + mn] = (f16)v;
            }
    __syncthreads();  // Ebuf ready

    // ---- vectorized e' store from Ebuf (skipped when dead, e.g. last layer)
    if (oute) {
#pragma unroll
        for (int it = 0; it < 4; ++it) {
            int u = it * 256 + t, row = u >> 4, k = (u & 15) * 8, gr = rbase + row;
            if (gr < NE) {
                half8 v = *(const half8*)(Ebuf + row * SH + k);
                *(half8*)(oute + (size_t)gr * 128 + k) = v;
            }
        }
    }

    // ---- fused P/Q GEMM: one pass over Ebuf fragments feeds both weight sets
    f32x4 aQ[4][2];
    {
        float bb0 = bPp[n0 + mn], bb1 = bPp[n0 + 16 + mn];
#pragma unroll
        for (int mt = 0; mt < 4; ++mt) {
            acc[mt][0] = (f32x4){bb0, bb0, bb0, bb0};
            acc[mt][1] = (f32x4){bb1, bb1, bb1, bb1};
            aQ[mt][0] = (f32x4){0.f, 0.f, 0.f, 0.f};
            aQ[mt][1] = (f32x4){0.f, 0.f, 0.f, 0.f};
        }
    }
#pragma unroll
    for (int kc = 0; kc < 4; ++kc) {
        half8 wPA = *(const half8*)(wpq + (size_t)(n0 + mn) * 128 + kc * 32 + quad * 8);
        half8 wPB = *(const half8*)(wpq + (size_t)(n0 + 16 + mn) * 128 + kc * 32 + quad * 8);
        half8 wQA = *(const half8*)(wpq + 16384 + (size_t)(n0 + mn) * 128 + kc * 32 + quad * 8);
        half8 wQB = *(const half8*)(wpq + 16384 + (size_t)(n0 + 16 + mn) * 128 + kc * 32 + quad * 8);
        half8 af[4];
#pragma unroll
        for (int mt = 0; mt < 4; ++mt)
            af[mt] = *(const half8*)(Ebuf + (mt * 16 + mn) * SH + kc * 32 + quad * 8);
#pragma unroll
        for (int mt = 0; mt < 4; ++mt) {
            acc[mt][0] = __builtin_amdgcn_mfma_f32_16x16x32_f16(af[mt], wPA, acc[mt][0], 0, 0, 0);
            acc[mt][1] = __builtin_amdgcn_mfma_f32_16x16x32_f16(af[mt], wPB, acc[mt][1], 0, 0, 0);
            aQ[mt][0] = __builtin_amdgcn_mfma_f32_16x16x32_f16(af[mt], wQA, aQ[mt][0], 0, 0, 0);
            aQ[mt][1] = __builtin_amdgcn_mfma_f32_16x16x32_f16(af[mt], wQB, aQ[mt][1], 0, 0, 0);
        }
    }
#pragma unroll
    for (int mt = 0; mt < 4; ++mt)
#pragma unroll
        for (int nt = 0; nt < 2; ++nt)
#pragma unroll
            for (int r = 0; r < 4; ++r) {
                int gr = rbase + mt * 16 + quad * 4 + r;
                if (gr < NE) {
                    Pout[(size_t)gr * 128 + n0 + nt * 16 + mn] = (f16)acc[mt][nt][r];
                    Qout[(size_t)gr * 128 + n0 + nt * 16 + mn] = (f16)aQ[mt][nt][r];
                }
            }
}

// one predictor tile: h1=relu(P1[i]+Q1[j]); h2=relu(h1@W2+b2); logit=h2@w3+b3; sigmoid
__device__ __forceinline__ void pred_tile(const KP& p, char* SMEM, float* w3s,
                                          float* psum, int tile, float b3v) {
    constexpr int SA = 136, SO = 133;
    f16* Abuf = (f16*)SMEM;
    float* Obuf = (float*)SMEM;
    const int t = threadIdx.x, lane = t & 63, wave = t >> 6;
    const int quad = lane >> 4, mn = lane & 15, n0 = wave * 32;
    const int rbase = tile << 6;
    // ---- gather staging: all indices first (one latency hop), then all 8 row
    // loads in flight (second hop), then combine+store.
    {
        int ii[4], jj[4];
        bool ok[4];
#pragma unroll
        for (int it = 0; it < 4; ++it) {
            int u = it * 256 + t, row = u >> 4, gr = rbase + row;
            ok[it] = gr < NC;
            int g2 = ok[it] ? gr : 0;
            ii[it] = p.cand_i[g2];
            jj[it] = p.cand_j[g2];
        }
        half8 av[4], bv[4];
#pragma unroll
        for (int it = 0; it < 4; ++it) {
            int u = it * 256 + t, k = (u & 15) * 8;
            av[it] = *(const half8*)(p.P1 + (size_t)ii[it] * 128 + k);
            bv[it] = *(const half8*)(p.Q1 + (size_t)jj[it] * 128 + k);
        }
#pragma unroll
        for (int it = 0; it < 4; ++it) {
            int u = it * 256 + t, row = u >> 4, k = (u & 15) * 8;
            half8 v = {};
            if (ok[it]) {
#pragma unroll
                for (int x = 0; x < 8; ++x)
                    v[x] = (f16)fmaxf((float)av[it][x] + (float)bv[it][x], 0.f);
            }
            *(half8*)(Abuf + row * SA + k) = v;
        }
    }
    __syncthreads();
    f32x4 acc[4][2];
    {
        float bb0 = p.pred_b2[n0 + mn], bb1 = p.pred_b2[n0 + 16 + mn];
#pragma unroll
        for (int mt = 0; mt < 4; ++mt) {
            acc[mt][0] = (f32x4){bb0, bb0, bb0, bb0};
            acc[mt][1] = (f32x4){bb1, bb1, bb1, bb1};
        }
    }
    {
        const f16* wrA = p.wt + OFF_PREDW2 + (size_t)(n0 + mn) * 128 + quad * 8;
        const f16* wrB = p.wt + OFF_PREDW2 + (size_t)(n0 + 16 + mn) * 128 + quad * 8;
        half8 wA = *(const half8*)(wrA);
        half8 wB = *(const half8*)(wrB);
#pragma unroll
        for (int kc = 0; kc < 4; ++kc) {
            half8 wAn = {}, wBn = {};
            if (kc + 1 < 4) {
                wAn = *(const half8*)(wrA + (kc + 1) * 32);
                wBn = *(const half8*)(wrB + (kc + 1) * 32);
            }
            half8 af[4];
#pragma unroll
            for (int mt = 0; mt < 4; ++mt)
                af[mt] = *(const half8*)(Abuf + (mt * 16 + mn) * SA + kc * 32 + quad * 8);
#pragma unroll
            for (int mt = 0; mt < 4; ++mt) {
                acc[mt][0] = __builtin_amdgcn_mfma_f32_16x16x32_f16(af[mt], wA, acc[mt][0], 0, 0, 0);
                acc[mt][1] = __builtin_amdgcn_mfma_f32_16x16x32_f16(af[mt], wB, acc[mt][1], 0, 0, 0);
            }
            wA = wAn; wB = wBn;
        }
    }
    __syncthreads();  // Abuf reads done before aliased Obuf writes
#pragma unroll
    for (int mt = 0; mt < 4; ++mt)
#pragma unroll
        for (int nt = 0; nt < 2; ++nt)
#pragma unroll
            for (int r = 0; r < 4; ++r)
                Obuf[(mt * 16 + quad * 4 + r) * SO + n0 + nt * 16 + mn] =
                    fmaxf(acc[mt][nt][r], 0.f);
    __syncthreads();
    {
        int row = t & 63, q4 = t >> 6;
        float s = 0.f;
#pragma unroll
        for (int i = 0; i < 32; ++i)
            s += Obuf[row * SO + q4 * 32 + i] * w3s[q4 * 32 + i];
        psum[t] = s;
    }
    __syncthreads();
    if (t < 64) {
        int gr = rbase + t;
        if (gr < NC) {
            float lg = psum[t] + psum[t + 64] + psum[t + 128] + psum[t + 192] + b3v;
            p.outL[gr] = lg;
            p.outP[gr] = 1.f / (1.f + expf(-lg));
        }
    }
}

__device__ __forceinline__ void upd_layer_ptrs(const KP& p, int l,
    const f16*& ein, f16*& eout, const f16*& Pin, const f16*& Qin,
    f16*& Pout, f16*& Qout, const f16*& wpq, const float*& bP) {
    ein = (l & 1) ? p.eB : p.eA;
    eout = (l == 2) ? nullptr : ((l & 1) ? p.eA : p.eB);  // l=2 e' is dead
    Pin = (l & 1) ? p.P1 : p.P0;
    Qin = (l & 1) ? p.Q1 : p.Q0;
    Pout = (l & 1) ? p.P0 : p.P1;
    Qout = (l & 1) ? p.Q0 : p.Q1;
    wpq = (l < 2) ? (p.wt + OFF_MSGPQ + (l + 1) * 32768) : (p.wt + OFF_PREDPQ);
    bP = (l < 2) ? (p.msg_b1 + (l + 1) * 128) : p.pred_b1;
}

// ---------------- plain launches ----------------
__global__ void k_prep(KP p) {
    int gid = blockIdx.x * 256 + threadIdx.x;
    if (gid < PTOT) prep_item(p, gid);
}
// encoder + PQ0 tile (raw f32 input), then grid-stride degseg over NA
__global__ __launch_bounds__(256, 4) void k_encdeg(KP p) {
    __shared__ __align__(16) char SMEM[34816];
    do_tile<64, false, true>(SMEM, blockIdx.x, nullptr, p.edge_features,
                             nullptr, nullptr, nullptr, nullptr, nullptr,
                             p.wt + OFF_ENC1, 64, p.enc_b1, p.wt + OFF_ENC2, p.enc_b2, false,
                             p.eA, p.wt + OFF_MSGPQ, p.msg_b1, p.P0, p.Q0);
    const int nthr = gridDim.x * 256;
    for (int i = blockIdx.x * 256 + threadIdx.x; i < NA; i += nthr) degseg_item(p, i);
}

// fused layer: in-tile channel-split gather agg + update MLP + P/Q projections
__global__ __launch_bounds__(256, 4) void k_layer(KP p, int l) {
    __shared__ __align__(16) char SMEM[34816];
    const f16 *ein, *Pin, *Qin, *wpq;
    f16 *eout, *Pout, *Qout;
    const float* bP;
    upd_layer_ptrs(p, l, ein, eout, Pin, Qin, Pout, Qout, wpq, bP);
    do_tile<256, true, false>(SMEM, blockIdx.x, ein, nullptr,
                              Pin, Qin, p.adj_src, p.segStart, p.segEnd,
                              p.wt + OFF_UPD1 + l * 32768, 256, p.fbias + l * 128,
                              p.wt + OFF_UPD2 + l * 16384, p.upd_b2 + l * 128, true,
                              eout, wpq, bP, Pout, Qout);
}
__global__ __launch_bounds__(256, 4) void k_pred(KP p) {
    __shared__ __align__(16) char SMEM[34816];
    __shared__ float w3s[128];
    __shared__ float psum[256];
    if (threadIdx.x < 128) w3s[threadIdx.x] = p.pred_W3[threadIdx.x];
    float b3v = p.pred_b3[0];
    pred_tile(p, SMEM, w3s, psum, blockIdx.x, b3v);
}

// ---------------- host ----------------
extern "C" void kernel_launch(void* const* d_in, const int* in_sizes, int n_in,
                              void* d_out, int out_size, void* d_ws, size_t ws_size,
                              hipStream_t stream) {
    KP p;
    p.edge_features = (const float*)d_in[0];
    p.adj_dst = (const int*)d_in[1];
    p.adj_src = (const int*)d_in[2];
    p.cand_i = (const int*)d_in[3];
    p.cand_j = (const int*)d_in[4];
    const float* enc_W1 = (const float*)d_in[5];
    p.enc_b1 = (const float*)d_in[6];
    const float* enc_W2 = (const float*)d_in[7];
    p.enc_b2 = (const float*)d_in[8];
    const float* msg_W1 = (const float*)d_in[9];
    p.msg_b1 = (const float*)d_in[10];
    p.msg_W2 = (const float*)d_in[11];
    p.msg_b2 = (const float*)d_in[12];
    p.upd_W1 = (const float*)d_in[13];
    p.upd_b1 = (const float*)d_in[14];
    const float* upd_W2 = (const float*)d_in[15];
    p.upd_b2 = (const float*)d_in[16];
    const float* pred_W1 = (const float*)d_in[17];
    p.pred_b1 = (const float*)d_in[18];
    const float* pred_W2 = (const float*)d_in[19];
    p.pred_b2 = (const float*)d_in[20];
    p.pred_W3 = (const float*)d_in[21];
    p.pred_b3 = (const float*)d_in[22];

    char* ws = (char*)d_ws;
    size_t off = 0;
    auto alloc = [&](size_t bytes) -> void* {
        void* q = ws + off;
        off = (off + bytes + 255) & ~(size_t)255;
        return q;
    };
    p.wt = (f16*)alloc((size_t)TOTAL_WT * 2);
    p.fbias = (float*)alloc(3 * 128 * 4);
    p.eA = (f16*)alloc((size_t)NE * 128 * 2);
    p.eB = (f16*)alloc((size_t)NE * 128 * 2);
    p.P0 = (f16*)alloc((size_t)NE * 128 * 2);
    p.Q0 = (f16*)alloc((size_t)NE * 128 * 2);
    p.P1 = (f16*)alloc((size_t)NE * 128 * 2);
    p.Q1 = (f16*)alloc((size_t)NE * 128 * 2);
    p.segStart = (int*)alloc((size_t)NE * 4);
    p.segEnd = (int*)alloc((size_t)NE * 4);
    p.outP = (float*)d_out;
    p.outL = (float*)d_out + NC;

    int idx = 0, c = 0;
    auto addj = [&](const float* s, int K, int o, int st) {
        p.wsrc[idx] = s; p.wK[idx] = K; p.wOff[idx] = o;
        p.wStr[idx] = st; p.wCum[idx] = c;
        c += K * 128; idx++;
    };
    addj(enc_W1, 64, OFF_ENC1, 64);
    addj(enc_W2, 128, OFF_ENC2, 128);
    for (int l = 0; l < 3; ++l) addj(msg_W1 + (size_t)l * 32768, 128, OFF_MSGPQ + l * 32768, 128);
    for (int l = 0; l < 3; ++l) addj(msg_W1 + (size_t)l * 32768 + 16384, 128, OFF_MSGPQ + l * 32768 + 16384, 128);
    for (int l = 0; l < 3; ++l) addj(p.upd_W1 + (size_t)l * 32768, 128, OFF_UPD1 + l * 32768, 256);
    for (int l = 0; l < 3; ++l) addj(upd_W2 + (size_t)l * 16384, 128, OFF_UPD2 + l * 16384, 128);
    addj(pred_W1, 128, OFF_PREDPQ, 128);
    addj(pred_W1 + 16384, 128, OFF_PREDPQ + 16384, 128);
    addj(pred_W2, 128, OFF_PREDW2, 128);
    for (int i = idx; i <= 20; ++i) p.wCum[i] = c;  // c == 270336 == R_WT

    const int tilesNE = (NE + 63) / 64;     // 782
    const int tilesNC = (NC + 63) / 64;     // 1563
    k_prep<<<(PTOT + 255) / 256, 256, 0, stream>>>(p);
    k_encdeg<<<tilesNE, 256, 0, stream>>>(p);
    for (int l = 0; l < 3; ++l) k_layer<<<tilesNE, 256, 0, stream>>>(p, l);
    k_pred<<<tilesNC, 256, 0, stream>>>(p);

    (void)in_sizes; (void)n_in; (void)out_size; (void)ws_size;
}

// Round 10
// 309.707 us; speedup vs baseline: 1.3450x; 1.1324x over previous
//
#include <hip/hip_runtime.h>
#include <hip/hip_bf16.h>

#define NE 50000
#define NA 800000
#define NC 100000

typedef _Float16 f16;
typedef f16 half8 __attribute__((ext_vector_type(8)));
typedef f16 f16x2 __attribute__((ext_vector_type(2)));
typedef f16 f16x4 __attribute__((ext_vector_type(4)));
typedef float f32x4 __attribute__((ext_vector_type(4)));

// f16-element offsets inside the converted-weight arena
#define OFF_ENC1 0
#define OFF_ENC2 8192
#define OFF_MSGPQ 24576    // 3 layers x 32768 (P block 16384 + Q block 16384)
#define OFF_UPD1 122880    // 3 layers x 32768, fused layout [n][256]
#define OFF_UPD2 221184    // 3 layers x 16384
#define OFF_PREDPQ 270336  // 32768
#define OFF_PREDW2 303104  // 16384
#define TOTAL_WT 319488

#define R_FUSE 49536       // 3*129 groups x 128 threads
#define R_WT 270336
#define R_Z 50000
#define PTOT (R_FUSE + R_WT + R_Z)

struct KP {
    const float* edge_features;
    const int *adj_dst, *adj_src, *cand_i, *cand_j;
    const float *enc_b1, *enc_b2;
    const float *msg_b1, *msg_W2, *msg_b2;
    const float *upd_W1, *upd_b1, *upd_b2;
    const float *pred_b1, *pred_b2, *pred_W3, *pred_b3;
    f16* wt;
    float* fbias;
    f16 *eA, *eB, *P0, *Q0, *P1, *Q1;
    int *segStart, *segEnd;
    float *outP, *outL;
    const float* wsrc[20];
    int wK[20], wOff[20], wStr[20], wCum[21];
};

// ---------------- shared device bodies ----------------

__device__ __forceinline__ void prep_item(const KP& p, int gid) {
    if (gid < R_FUSE) {
        // fused W2U = msg_W2 @ upd_W1[128:256] and fbias; coalesced per 128-group
        int g = gid >> 7, n = gid & 127;
        int l = g / 129, kk = g % 129;
        const float* U1b = p.upd_W1 + (size_t)l * 32768 + 16384;
        if (kk < 128) {
            const float* w2row = p.msg_W2 + (size_t)l * 16384 + (size_t)kk * 128;
            float s = 0.f;
            for (int m = 0; m < 128; ++m) s += w2row[m] * U1b[m * 128 + n];
            p.wt[OFF_UPD1 + l * 32768 + n * 256 + 128 + kk] = (f16)s;
        } else {
            const float* b2 = p.msg_b2 + l * 128;
            float s = p.upd_b1[l * 128 + n];
            for (int m = 0; m < 128; ++m) s += b2[m] * U1b[m * 128 + n];
            p.fbias[l * 128 + n] = s;
        }
    } else if (gid < R_FUSE + R_WT) {
        int e = gid - R_FUSE;
        int j = 0;
#pragma unroll
        for (int i = 1; i < 20; ++i) j += (e >= p.wCum[i]) ? 1 : 0;
        int r = e - p.wCum[j];
        int K = p.wK[j];
        int k = r % K, n = r / K;
        p.wt[p.wOff[j] + n * p.wStr[j] + k] = (f16)p.wsrc[j][(size_t)k * 128 + n];
    } else if (gid < PTOT) {
        int z = gid - (R_FUSE + R_WT);
        p.segStart[z] = 0;
        p.segEnd[z] = 0;
    }
}

__device__ __forceinline__ void degseg_item(const KP& p, int i) {
    int d = p.adj_dst[i];
    if (i == 0 || p.adj_dst[i - 1] != d) p.segStart[d] = i;
    if (i == NA - 1 || p.adj_dst[i + 1] != d) p.segEnd[d] = i + 1;
}

// one 64-row tile: [in-tile gather agg]? -> GEMM1(K1) -> relu -> GEMM2 -> e'
// -> fused P/Q GEMM.
// AGG: gather right half of A (cols 128..255) via quarter-wave-per-dst
//      shfl-broadcast pipelined gather from Pin/Qin.
// F32IN: stage A from raw f32 in0f (convert on the fly) instead of f16 in0.
template <int K1, bool AGG, bool F32IN>
__device__ __forceinline__ void do_tile(
    char* SMEM, int tile, const f16* __restrict__ in0, const float* __restrict__ in0f,
    const f16* __restrict__ Pin, const f16* __restrict__ Qin,
    const int* __restrict__ adj_src, const int* __restrict__ segStart,
    const int* __restrict__ segEnd,
    const f16* __restrict__ w1t, const int w1s, const float* __restrict__ b1v,
    const f16* __restrict__ w2t, const float* __restrict__ b2v, const bool reluOut,
    f16* __restrict__ oute,
    const f16* __restrict__ wpq, const float* __restrict__ bPp,
    f16* __restrict__ Pout, f16* __restrict__ Qout) {
    constexpr int SA = K1 + 8;   // f16 stride
    constexpr int SH = 136;      // f16 stride for H/E
    constexpr int NKC = K1 / 32;
    f16* Abuf = (f16*)SMEM;
    f16* Hbuf = (f16*)SMEM;                  // aliases Abuf low (dead after GEMM1)
    f16* Ebuf = (f16*)(SMEM + 17408);        // after Hbuf; overlaps dead Abuf top
    const int t = threadIdx.x, lane = t & 63, wave = t >> 6;
    const int quad = lane >> 4, mn = lane & 15, n0 = wave * 32;
    const int rbase = tile << 6;

    // ---- in-tile gather agg first: its 3-hop chain (seg -> idx -> Q-row)
    // starts issuing immediately; the independent staging below fills stalls.
    if constexpr (AGG) {
        const int cl = mn;             // channel-lane 0..15, channels cl*8..cl*8+7
        const int qb = quad << 4;      // quarter base lane within wave
#pragma unroll
        for (int g = 0; g < 4; ++g) {
            const int drow = wave * 16 + g * 4 + quad;
            const int dst = rbase + drow;
            const bool ok = dst < NE;  // uniform within quarter
            if (ok) {
                const int s = segStart[dst];
                const int deg = segEnd[dst] - s;
                const bool iso = (deg == 0);
                const int d1 = iso ? 1 : deg;
                // lane-parallel coalesced index preload (up to 48)
                int i0 = (cl < deg) ? adj_src[s + cl] : 0;
                int i1 = (cl + 16 < deg) ? adj_src[s + cl + 16] : 0;
                int i2 = (cl + 32 < deg) ? adj_src[s + cl + 32] : 0;
                half8 pv = *(const half8*)(Pin + (size_t)dst * 128 + cl * 8);
                float x[8] = {0.f, 0.f, 0.f, 0.f, 0.f, 0.f, 0.f, 0.f};
                const int nb = min((d1 + 7) >> 3, 6);
                half8 qA[8], qB[8];  // 2-slot pipeline, static names

                auto issue = [&](int b, half8* qq) {
                    int ireg = (b < 2) ? i0 : (b < 4) ? i1 : i2;
                    const int base = (b & 1) * 8;
#pragma unroll
                    for (int u = 0; u < 8; ++u) {
                        int sj = __shfl(ireg, qb + base + u, 64);
                        int j = b * 8 + u;
                        int idx = iso ? dst : ((j < d1) ? sj : dst);
                        qq[u] = *(const half8*)(Qin + (size_t)idx * 128 + cl * 8);
                    }
                };
                auto consume = [&](int b, half8* qq) {
#pragma unroll
                    for (int u = 0; u < 8; ++u) {
                        if (b * 8 + u < d1) {
#pragma unroll
                            for (int c = 0; c < 8; ++c)
                                x[c] += fmaxf((float)pv[c] + (float)qq[u][c], 0.f);
                        }
                    }
                };
                issue(0, qA);
#pragma unroll
                for (int b = 0; b < 6; ++b) {
                    if (b < nb) {
                        half8* cur = (b & 1) ? qB : qA;
                        half8* nxt = (b & 1) ? qA : qB;
                        if (b + 1 < nb) issue(b + 1, nxt);
                        consume(b, cur);
                    }
                }
                // overflow tail (deg > 48): statistically near-impossible
                for (int j = 48; j < d1; ++j) {
                    int idx = adj_src[s + j];
                    half8 qj = *(const half8*)(Qin + (size_t)idx * 128 + cl * 8);
#pragma unroll
                    for (int c = 0; c < 8; ++c)
                        x[c] += fmaxf((float)pv[c] + (float)qj[c], 0.f);
                }
                const float sc = 1.f / (float)d1;
                half8 o;
#pragma unroll
                for (int c = 0; c < 8; ++c) o[c] = (f16)(x[c] * sc);
                *(half8*)(Abuf + drow * SA + 128 + cl * 8) = o;
            }
        }
    }

    // ---- stage A-tile left half (or all of it for K1==64) from in0/in0f
    if constexpr (F32IN) {
        // 64 rows x 64 f32 cols, convert to f16
#pragma unroll
        for (int it = 0; it < 4; ++it) {
            int u = it * 256 + t, row = u >> 4, k = (u & 15) * 4, gr = rbase + row;
            f32x4 v = {};
            if (gr < NE) v = *(const f32x4*)(in0f + (size_t)gr * 64 + k);
            f16x4 o = {(f16)v[0], (f16)v[1], (f16)v[2], (f16)v[3]};
            *(f16x4*)(Abuf + row * SA + k) = o;
        }
    } else if constexpr (K1 == 64) {
#pragma unroll
        for (int it = 0; it < 2; ++it) {
            int u = it * 256 + t, row = u >> 3, k = (u & 7) * 8, gr = rbase + row;
            half8 v = {};
            if (gr < NE) v = *(const half8*)(in0 + (size_t)gr * 64 + k);
            *(half8*)(Abuf + row * SA + k) = v;
        }
    } else {
#pragma unroll
        for (int it = 0; it < 4; ++it) {
            int u = it * 256 + t, row = u >> 4, k = (u & 15) * 8, gr = rbase + row;
            half8 v = {};
            if (gr < NE) v = *(const half8*)(in0 + (size_t)gr * 128 + k);
            *(half8*)(Abuf + row * SA + k) = v;
        }
    }
    __syncthreads();

    // ---- GEMM1: [64 x K1] @ [K1 x 128] + b1, relu -> Hbuf (weights dbuf'd)
    f32x4 acc[4][2];
    {
        float bb0 = b1v[n0 + mn], bb1 = b1v[n0 + 16 + mn];
#pragma unroll
        for (int mt = 0; mt < 4; ++mt) {
            acc[mt][0] = (f32x4){bb0, bb0, bb0, bb0};
            acc[mt][1] = (f32x4){bb1, bb1, bb1, bb1};
        }
    }
    {
        const f16* wrA = w1t + (size_t)(n0 + mn) * w1s + quad * 8;
        const f16* wrB = w1t + (size_t)(n0 + 16 + mn) * w1s + quad * 8;
        half8 wA = *(const half8*)(wrA);
        half8 wB = *(const half8*)(wrB);
#pragma unroll
        for (int kc = 0; kc < NKC; ++kc) {
            half8 wAn = {}, wBn = {};
            if (kc + 1 < NKC) {
                wAn = *(const half8*)(wrA + (kc + 1) * 32);
                wBn = *(const half8*)(wrB + (kc + 1) * 32);
            }
            half8 af[4];
#pragma unroll
            for (int mt = 0; mt < 4; ++mt)
                af[mt] = *(const half8*)(Abuf + (mt * 16 + mn) * SA + kc * 32 + quad * 8);
#pragma unroll
            for (int mt = 0; mt < 4; ++mt) {
                acc[mt][0] = __builtin_amdgcn_mfma_f32_16x16x32_f16(af[mt], wA, acc[mt][0], 0, 0, 0);
                acc[mt][1] = __builtin_amdgcn_mfma_f32_16x16x32_f16(af[mt], wB, acc[mt][1], 0, 0, 0);
            }
            wA = wAn; wB = wBn;
        }
    }
    __syncthreads();  // A reads done before aliased Hbuf writes
#pragma unroll
    for (int mt = 0; mt < 4; ++mt)
#pragma unroll
        for (int nt = 0; nt < 2; ++nt)
#pragma unroll
            for (int r = 0; r < 4; ++r)
                Hbuf[(mt * 16 + quad * 4 + r) * SH + n0 + nt * 16 + mn] =
                    (f16)fmaxf(acc[mt][nt][r], 0.f);
    __syncthreads();

    // ---- GEMM2: [64x128]@[128x128] + b2 (+relu) -> Ebuf (weights dbuf'd)
    {
        float bb0 = b2v[n0 + mn], bb1 = b2v[n0 + 16 + mn];
#pragma unroll
        for (int mt = 0; mt < 4; ++mt) {
            acc[mt][0] = (f32x4){bb0, bb0, bb0, bb0};
            acc[mt][1] = (f32x4){bb1, bb1, bb1, bb1};
        }
    }
    {
        const f16* wrA = w2t + (size_t)(n0 + mn) * 128 + quad * 8;
        const f16* wrB = w2t + (size_t)(n0 + 16 + mn) * 128 + quad * 8;
        half8 wA = *(const half8*)(wrA);
        half8 wB = *(const half8*)(wrB);
#pragma unroll
        for (int kc = 0; kc < 4; ++kc) {
            half8 wAn = {}, wBn = {};
            if (kc + 1 < 4) {
                wAn = *(const half8*)(wrA + (kc + 1) * 32);
                wBn = *(const half8*)(wrB + (kc + 1) * 32);
            }
            half8 af[4];
#pragma unroll
            for (int mt = 0; mt < 4; ++mt)
                af[mt] = *(const half8*)(Hbuf + (mt * 16 + mn) * SH + kc * 32 + quad * 8);
#pragma unroll
            for (int mt = 0; mt < 4; ++mt) {
                acc[mt][0] = __builtin_amdgcn_mfma_f32_16x16x32_f16(af[mt], wA, acc[mt][0], 0, 0, 0);
                acc[mt][1] = __builtin_amdgcn_mfma_f32_16x16x32_f16(af[mt], wB, acc[mt][1], 0, 0, 0);
            }
            wA = wAn; wB = wBn;
        }
    }
#pragma unroll
    for (int mt = 0; mt < 4; ++mt)
#pragma unroll
        for (int nt = 0; nt < 2; ++nt)
#pragma unroll
            for (int r = 0; r < 4; ++r) {
                float v = acc[mt][nt][r];
                if (reluOut) v = fmaxf(v, 0.f);
                Ebuf[(mt * 16 + quad * 4 + r) * SH + n0 + nt * 16 + mn] = (f16)v;
            }
    __syncthreads();  // Ebuf ready

    // ---- vectorized e' store from Ebuf (skipped when dead, e.g. last layer)
    if (oute) {
#pragma unroll
        for (int it = 0; it < 4; ++it) {
            int u = it * 256 + t, row = u >> 4, k = (u & 15) * 8, gr = rbase + row;
            if (gr < NE) {
                half8 v = *(const half8*)(Ebuf + row * SH + k);
                *(half8*)(oute + (size_t)gr * 128 + k) = v;
            }
        }
    }

    // ---- fused P/Q GEMM: one pass over Ebuf fragments feeds both weight sets
    f32x4 aQ[4][2];
    {
        float bb0 = bPp[n0 + mn], bb1 = bPp[n0 + 16 + mn];
#pragma unroll
        for (int mt = 0; mt < 4; ++mt) {
            acc[mt][0] = (f32x4){bb0, bb0, bb0, bb0};
            acc[mt][1] = (f32x4){bb1, bb1, bb1, bb1};
            aQ[mt][0] = (f32x4){0.f, 0.f, 0.f, 0.f};
            aQ[mt][1] = (f32x4){0.f, 0.f, 0.f, 0.f};
        }
    }
#pragma unroll
    for (int kc = 0; kc < 4; ++kc) {
        half8 wPA = *(const half8*)(wpq + (size_t)(n0 + mn) * 128 + kc * 32 + quad * 8);
        half8 wPB = *(const half8*)(wpq + (size_t)(n0 + 16 + mn) * 128 + kc * 32 + quad * 8);
        half8 wQA = *(const half8*)(wpq + 16384 + (size_t)(n0 + mn) * 128 + kc * 32 + quad * 8);
        half8 wQB = *(const half8*)(wpq + 16384 + (size_t)(n0 + 16 + mn) * 128 + kc * 32 + quad * 8);
        half8 af[4];
#pragma unroll
        for (int mt = 0; mt < 4; ++mt)
            af[mt] = *(const half8*)(Ebuf + (mt * 16 + mn) * SH + kc * 32 + quad * 8);
#pragma unroll
        for (int mt = 0; mt < 4; ++mt) {
            acc[mt][0] = __builtin_amdgcn_mfma_f32_16x16x32_f16(af[mt], wPA, acc[mt][0], 0, 0, 0);
            acc[mt][1] = __builtin_amdgcn_mfma_f32_16x16x32_f16(af[mt], wPB, acc[mt][1], 0, 0, 0);
            aQ[mt][0] = __builtin_amdgcn_mfma_f32_16x16x32_f16(af[mt], wQA, aQ[mt][0], 0, 0, 0);
            aQ[mt][1] = __builtin_amdgcn_mfma_f32_16x16x32_f16(af[mt], wQB, aQ[mt][1], 0, 0, 0);
        }
    }
#pragma unroll
    for (int mt = 0; mt < 4; ++mt)
#pragma unroll
        for (int nt = 0; nt < 2; ++nt)
#pragma unroll
            for (int r = 0; r < 4; ++r) {
                int gr = rbase + mt * 16 + quad * 4 + r;
                if (gr < NE) {
                    Pout[(size_t)gr * 128 + n0 + nt * 16 + mn] = (f16)acc[mt][nt][r];
                    Qout[(size_t)gr * 128 + n0 + nt * 16 + mn] = (f16)aQ[mt][nt][r];
                }
            }
}

// one predictor tile: h1=relu(P1[i]+Q1[j]); h2=relu(h1@W2+b2); logit=h2@w3+b3; sigmoid
__device__ __forceinline__ void pred_tile(const KP& p, char* SMEM, float* w3s,
                                          float* psum, int tile, float b3v) {
    constexpr int SA = 136, SO = 133;
    f16* Abuf = (f16*)SMEM;
    float* Obuf = (float*)SMEM;
    const int t = threadIdx.x, lane = t & 63, wave = t >> 6;
    const int quad = lane >> 4, mn = lane & 15, n0 = wave * 32;
    const int rbase = tile << 6;
    // ---- gather staging: all indices first (one latency hop), then all 8 row
    // loads in flight (second hop), then combine+store.
    {
        int ii[4], jj[4];
        bool ok[4];
#pragma unroll
        for (int it = 0; it < 4; ++it) {
            int u = it * 256 + t, row = u >> 4, gr = rbase + row;
            ok[it] = gr < NC;
            int g2 = ok[it] ? gr : 0;
            ii[it] = p.cand_i[g2];
            jj[it] = p.cand_j[g2];
        }
        half8 av[4], bv[4];
#pragma unroll
        for (int it = 0; it < 4; ++it) {
            int u = it * 256 + t, k = (u & 15) * 8;
            av[it] = *(const half8*)(p.P1 + (size_t)ii[it] * 128 + k);
            bv[it] = *(const half8*)(p.Q1 + (size_t)jj[it] * 128 + k);
        }
#pragma unroll
        for (int it = 0; it < 4; ++it) {
            int u = it * 256 + t, row = u >> 4, k = (u & 15) * 8;
            half8 v = {};
            if (ok[it]) {
#pragma unroll
                for (int x = 0; x < 8; ++x)
                    v[x] = (f16)fmaxf((float)av[it][x] + (float)bv[it][x], 0.f);
            }
            *(half8*)(Abuf + row * SA + k) = v;
        }
    }
    __syncthreads();
    f32x4 acc[4][2];
    {
        float bb0 = p.pred_b2[n0 + mn], bb1 = p.pred_b2[n0 + 16 + mn];
#pragma unroll
        for (int mt = 0; mt < 4; ++mt) {
            acc[mt][0] = (f32x4){bb0, bb0, bb0, bb0};
            acc[mt][1] = (f32x4){bb1, bb1, bb1, bb1};
        }
    }
    {
        const f16* wrA = p.wt + OFF_PREDW2 + (size_t)(n0 + mn) * 128 + quad * 8;
        const f16* wrB = p.wt + OFF_PREDW2 + (size_t)(n0 + 16 + mn) * 128 + quad * 8;
        half8 wA = *(const half8*)(wrA);
        half8 wB = *(const half8*)(wrB);
#pragma unroll
        for (int kc = 0; kc < 4; ++kc) {
            half8 wAn = {}, wBn = {};
            if (kc + 1 < 4) {
                wAn = *(const half8*)(wrA + (kc + 1) * 32);
                wBn = *(const half8*)(wrB + (kc + 1) * 32);
            }
            half8 af[4];
#pragma unroll
            for (int mt = 0; mt < 4; ++mt)
                af[mt] = *(const half8*)(Abuf + (mt * 16 + mn) * SA + kc * 32 + quad * 8);
#pragma unroll
            for (int mt = 0; mt < 4; ++mt) {
                acc[mt][0] = __builtin_amdgcn_mfma_f32_16x16x32_f16(af[mt], wA, acc[mt][0], 0, 0, 0);
                acc[mt][1] = __builtin_amdgcn_mfma_f32_16x16x32_f16(af[mt], wB, acc[mt][1], 0, 0, 0);
            }
            wA = wAn; wB = wBn;
        }
    }
    __syncthreads();  // Abuf reads done before aliased Obuf writes
#pragma unroll
    for (int mt = 0; mt < 4; ++mt)
#pragma unroll
        for (int nt = 0; nt < 2; ++nt)
#pragma unroll
            for (int r = 0; r < 4; ++r)
                Obuf[(mt * 16 + quad * 4 + r) * SO + n0 + nt * 16 + mn] =
                    fmaxf(acc[mt][nt][r], 0.f);
    __syncthreads();
    {
        int row = t & 63, q4 = t >> 6;
        float s = 0.f;
#pragma unroll
        for (int i = 0; i < 32; ++i)
            s += Obuf[row * SO + q4 * 32 + i] * w3s[q4 * 32 + i];
        psum[t] = s;
    }
    __syncthreads();
    if (t < 64) {
        int gr = rbase + t;
        if (gr < NC) {
            float lg = psum[t] + psum[t + 64] + psum[t + 128] + psum[t + 192] + b3v;
            p.outL[gr] = lg;
            p.outP[gr] = 1.f / (1.f + expf(-lg));
        }
    }
}

__device__ __forceinline__ void upd_layer_ptrs(const KP& p, int l,
    const f16*& ein, f16*& eout, const f16*& Pin, const f16*& Qin,
    f16*& Pout, f16*& Qout, const f16*& wpq, const float*& bP) {
    ein = (l & 1) ? p.eB : p.eA;
    eout = (l == 2) ? nullptr : ((l & 1) ? p.eA : p.eB);  // l=2 e' is dead
    Pin = (l & 1) ? p.P1 : p.P0;
    Qin = (l & 1) ? p.Q1 : p.Q0;
    Pout = (l & 1) ? p.P0 : p.P1;
    Qout = (l & 1) ? p.Q0 : p.Q1;
    wpq = (l < 2) ? (p.wt + OFF_MSGPQ + (l + 1) * 32768) : (p.wt + OFF_PREDPQ);
    bP = (l < 2) ? (p.msg_b1 + (l + 1) * 128) : p.pred_b1;
}

// ---------------- plain launches ----------------
__global__ void k_prep(KP p) {
    int gid = blockIdx.x * 256 + threadIdx.x;
    if (gid < PTOT) prep_item(p, gid);
}
// encoder + PQ0 tile (raw f32 input), then grid-stride degseg over NA
__global__ __launch_bounds__(256, 4) void k_encdeg(KP p) {
    __shared__ __align__(16) char SMEM[34816];
    do_tile<64, false, true>(SMEM, blockIdx.x, nullptr, p.edge_features,
                             nullptr, nullptr, nullptr, nullptr, nullptr,
                             p.wt + OFF_ENC1, 64, p.enc_b1, p.wt + OFF_ENC2, p.enc_b2, false,
                             p.eA, p.wt + OFF_MSGPQ, p.msg_b1, p.P0, p.Q0);
    const int nthr = gridDim.x * 256;
    for (int i = blockIdx.x * 256 + threadIdx.x; i < NA; i += nthr) degseg_item(p, i);
}

// fused layer: in-tile gather agg + update MLP + P/Q projections
__global__ __launch_bounds__(256, 4) void k_layer(KP p, int l) {
    __shared__ __align__(16) char SMEM[34816];
    const f16 *ein, *Pin, *Qin, *wpq;
    f16 *eout, *Pout, *Qout;
    const float* bP;
    upd_layer_ptrs(p, l, ein, eout, Pin, Qin, Pout, Qout, wpq, bP);
    do_tile<256, true, false>(SMEM, blockIdx.x, ein, nullptr,
                              Pin, Qin, p.adj_src, p.segStart, p.segEnd,
                              p.wt + OFF_UPD1 + l * 32768, 256, p.fbias + l * 128,
                              p.wt + OFF_UPD2 + l * 16384, p.upd_b2 + l * 128, true,
                              eout, wpq, bP, Pout, Qout);
}
__global__ __launch_bounds__(256, 4) void k_pred(KP p) {
    __shared__ __align__(16) char SMEM[34816];
    __shared__ float w3s[128];
    __shared__ float psum[256];
    if (threadIdx.x < 128) w3s[threadIdx.x] = p.pred_W3[threadIdx.x];
    float b3v = p.pred_b3[0];
    pred_tile(p, SMEM, w3s, psum, blockIdx.x, b3v);
}

// ---------------- host ----------------
extern "C" void kernel_launch(void* const* d_in, const int* in_sizes, int n_in,
                              void* d_out, int out_size, void* d_ws, size_t ws_size,
                              hipStream_t stream) {
    KP p;
    p.edge_features = (const float*)d_in[0];
    p.adj_dst = (const int*)d_in[1];
    p.adj_src = (const int*)d_in[2];
    p.cand_i = (const int*)d_in[3];
    p.cand_j = (const int*)d_in[4];
    const float* enc_W1 = (const float*)d_in[5];
    p.enc_b1 = (const float*)d_in[6];
    const float* enc_W2 = (const float*)d_in[7];
    p.enc_b2 = (const float*)d_in[8];
    const float* msg_W1 = (const float*)d_in[9];
    p.msg_b1 = (const float*)d_in[10];
    p.msg_W2 = (const float*)d_in[11];
    p.msg_b2 = (const float*)d_in[12];
    p.upd_W1 = (const float*)d_in[13];
    p.upd_b1 = (const float*)d_in[14];
    const float* upd_W2 = (const float*)d_in[15];
    p.upd_b2 = (const float*)d_in[16];
    const float* pred_W1 = (const float*)d_in[17];
    p.pred_b1 = (const float*)d_in[18];
    const float* pred_W2 = (const float*)d_in[19];
    p.pred_b2 = (const float*)d_in[20];
    p.pred_W3 = (const float*)d_in[21];
    p.pred_b3 = (const float*)d_in[22];

    char* ws = (char*)d_ws;
    size_t off = 0;
    auto alloc = [&](size_t bytes) -> void* {
        void* q = ws + off;
        off = (off + bytes + 255) & ~(size_t)255;
        return q;
    };
    p.wt = (f16*)alloc((size_t)TOTAL_WT * 2);
    p.fbias = (float*)alloc(3 * 128 * 4);
    p.eA = (f16*)alloc((size_t)NE * 128 * 2);
    p.eB = (f16*)alloc((size_t)NE * 128 * 2);
    p.P0 = (f16*)alloc((size_t)NE * 128 * 2);
    p.Q0 = (f16*)alloc((size_t)NE * 128 * 2);
    p.P1 = (f16*)alloc((size_t)NE * 128 * 2);
    p.Q1 = (f16*)alloc((size_t)NE * 128 * 2);
    p.segStart = (int*)alloc((size_t)NE * 4);
    p.segEnd = (int*)alloc((size_t)NE * 4);
    p.outP = (float*)d_out;
    p.outL = (float*)d_out + NC;

    int idx = 0, c = 0;
    auto addj = [&](const float* s, int K, int o, int st) {
        p.wsrc[idx] = s; p.wK[idx] = K; p.wOff[idx] = o;
        p.wStr[idx] = st; p.wCum[idx] = c;
        c += K * 128; idx++;
    };
    addj(enc_W1, 64, OFF_ENC1, 64);
    addj(enc_W2, 128, OFF_ENC2, 128);
    for (int l = 0; l < 3; ++l) addj(msg_W1 + (size_t)l * 32768, 128, OFF_MSGPQ + l * 32768, 128);
    for (int l = 0; l < 3; ++l) addj(msg_W1 + (size_t)l * 32768 + 16384, 128, OFF_MSGPQ + l * 32768 + 16384, 128);
    for (int l = 0; l < 3; ++l) addj(p.upd_W1 + (size_t)l * 32768, 128, OFF_UPD1 + l * 32768, 256);
    for (int l = 0; l < 3; ++l) addj(upd_W2 + (size_t)l * 16384, 128, OFF_UPD2 + l * 16384, 128);
    addj(pred_W1, 128, OFF_PREDPQ, 128);
    addj(pred_W1 + 16384, 128, OFF_PREDPQ + 16384, 128);
    addj(pred_W2, 128, OFF_PREDW2, 128);
    for (int i = idx; i <= 20; ++i) p.wCum[i] = c;  // c == 270336 == R_WT

    const int tilesNE = (NE + 63) / 64;     // 782
    const int tilesNC = (NC + 63) / 64;     // 1563
    k_prep<<<(PTOT + 255) / 256, 256, 0, stream>>>(p);
    k_encdeg<<<tilesNE, 256, 0, stream>>>(p);
    for (int l = 0; l < 3; ++l) k_layer<<<tilesNE, 256, 0, stream>>>(p, l);
    k_pred<<<tilesNC, 256, 0, stream>>>(p);

    (void)in_sizes; (void)n_in; (void)out_size; (void)ws_size;
}